// Round 11
// baseline (323.717 us; speedup 1.0000x reference)
//
#include <hip/hip_runtime.h>

#define EPSBN 1e-5f
#define AGG_BLOCKS 4096

using bf16x8 = __attribute__((ext_vector_type(8))) short;
using f32x4  = __attribute__((ext_vector_type(4))) float;

__device__ __forceinline__ unsigned short f2bf(float f) {
    unsigned u = __builtin_bit_cast(unsigned, f);
    unsigned r = (u + 0x7FFFu + ((u >> 16) & 1u)) >> 16;   // RTNE
    return (unsigned short)r;
}
__device__ __forceinline__ float bf2f(unsigned short s) {
    unsigned u = ((unsigned)s) << 16;
    return __builtin_bit_cast(float, u);
}

// ---------------- fused prep: W images (blocks 0-2) + degree/bucket hist (blocks 3+) ----------------

__global__ __launch_bounds__(256) void k_prep(const float* __restrict__ W0, const float* __restrict__ W1,
                                              const float* __restrict__ W2, unsigned short* __restrict__ Wimg,
                                              const int* __restrict__ dst, int E,
                                              int* __restrict__ deg, int* __restrict__ bcnt, int shift) {
    int tid = threadIdx.x;
    if (blockIdx.x < 3) {
        const float* W = (blockIdx.x == 0) ? W0 : (blockIdx.x == 1) ? W1 : W2;
        unsigned short* out = Wimg + (size_t)blockIdx.x * 16384;
        int n = tid & 127, kh = tid >> 7;
        const float* wp = &W[(kh * 64) * 128 + n];
        #pragma unroll
        for (int kb = 0; kb < 8; ++kb) {
            unsigned short t8[8];
            #pragma unroll
            for (int e = 0; e < 8; ++e)
                t8[e] = f2bf(wp[(kb * 8 + e) * 128]);
            int byte = (n * 256 + kh * 128 + kb * 16) ^ ((n & 7) << 4);
            *reinterpret_cast<uint4*>(reinterpret_cast<char*>(out) + byte) =
                *reinterpret_cast<const uint4*>(t8);
        }
        return;
    }
    __shared__ int lh[512];
    for (int i = tid; i < 512; i += 256) lh[i] = 0;
    __syncthreads();
    int b = blockIdx.x - 3;                      // 256 hist blocks
    for (int i = b * 256 + tid; i < E; i += 256 * 256) {
        int d = dst[i];
        atomicAdd(&deg[d], 1);
        atomicAdd(&lh[d >> shift], 1);
    }
    __syncthreads();
    for (int i = tid; i < 512; i += 256)
        if (lh[i]) atomicAdd(&bcnt[i], lh[i]);
}

// scan1 also emits dinv (deg already in hand)
__global__ void k_scan1(const int* __restrict__ deg, int N, int* __restrict__ rs, int* __restrict__ blk,
                        float* __restrict__ dinv) {
    __shared__ int sh[256];
    int tid = threadIdx.x;
    int i = blockIdx.x * 256 + tid;
    int v = (i < N) ? deg[i] : 0;
    if (i < N) dinv[i] = rsqrtf((float)(v + 1));     // +1 self-loop
    sh[tid] = v; __syncthreads();
    for (int off = 1; off < 256; off <<= 1) {
        int t = (tid >= off) ? sh[tid - off] : 0;
        __syncthreads();
        sh[tid] += t;
        __syncthreads();
    }
    if (i < N) rs[i] = sh[tid] - v;          // block-local exclusive
    if (tid == 255) blk[blockIdx.x] = sh[255];
}

// two independent exclusive scans in one dispatch
__global__ __launch_bounds__(1024) void k_scan2x(const int* __restrict__ blk, int nb, int* __restrict__ blkoff,
                                                 const int* __restrict__ bcnt, int nb2, int* __restrict__ boff) {
    __shared__ int sh[1024];
    const int* in = blockIdx.x ? bcnt : blk;
    int n = blockIdx.x ? nb2 : nb;
    int* outp = blockIdx.x ? boff : blkoff;
    int tid = threadIdx.x;
    int v = (tid < n) ? in[tid] : 0;
    sh[tid] = v; __syncthreads();
    for (int off = 1; off < 1024; off <<= 1) {
        int t = (tid >= off) ? sh[tid - off] : 0;
        __syncthreads();
        sh[tid] += t;
        __syncthreads();
    }
    if (tid < n) outp[tid] = sh[tid] - v; // exclusive
}

// ---------------- bucketed edge scatter ----------------

__global__ __launch_bounds__(256) void k_bscatter(const int* __restrict__ src, const int* __restrict__ dst, int E,
                                                  const int* __restrict__ boff, int* __restrict__ gcur,
                                                  uint2* __restrict__ ebuf, int shift) {
    __shared__ int lh[512], lb[512];
    int tid = threadIdx.x;
    int base = blockIdx.x * 2048;
    for (int i = tid; i < 512; i += 256) lh[i] = 0;
    __syncthreads();
    int ms[8], md[8];
    #pragma unroll
    for (int j = 0; j < 8; ++j) {
        int idx = base + j * 256 + tid;
        if (idx < E) {
            ms[j] = src[idx]; md[j] = dst[idx];
            atomicAdd(&lh[md[j] >> shift], 1);
        } else md[j] = -1;
    }
    __syncthreads();
    for (int b = tid; b < 512; b += 256) {
        int c = lh[b];
        lb[b] = c ? atomicAdd(&gcur[b], c) : 0;
    }
    __syncthreads();
    for (int i = tid; i < 512; i += 256) lh[i] = 0;
    __syncthreads();
    #pragma unroll
    for (int j = 0; j < 8; ++j) {
        if (md[j] >= 0) {
            int b = md[j] >> shift;
            int r = atomicAdd(&lh[b], 1);
            ebuf[boff[b] + lb[b] + r] = make_uint2((unsigned)ms[j], (unsigned)md[j]);
        }
    }
}

// ---------------- CSR fill: colw[pos] = (src, dinv[src]); rs fold of blkoff ----------------

__global__ __launch_bounds__(256) void k_fill2(const uint2* __restrict__ ebuf, const int* __restrict__ bcnt,
                                               const int* __restrict__ boff, const int* __restrict__ rs,
                                               const int* __restrict__ blkoff, const float* __restrict__ dinv,
                                               uint2* __restrict__ colw, int shift) {
    __shared__ int lcur[256];
    int b = blockIdx.x;
    int n0 = b << shift;
    int cnt = bcnt[b], s = boff[b];
    int span = 1 << shift;
    for (int i = threadIdx.x; i < span; i += 256) lcur[i] = 0;
    __syncthreads();
    for (int i = threadIdx.x; i < cnt; i += 256) {
        uint2 e = ebuf[s + i];
        int d = (int)e.y;
        int sv = (int)e.x;
        int pos = rs[d] + blkoff[d >> 8] + atomicAdd(&lcur[d - n0], 1);
        colw[pos] = make_uint2((unsigned)sv, __builtin_bit_cast(unsigned, dinv[sv]));
    }
}

// ---------------- MFMA GEMM: 64-row tiles (782 blocks, 48KB LDS) — round-6 proven ----------------

__global__ __launch_bounds__(256) void k_gemm(const unsigned short* __restrict__ Abf,
                                              const float* __restrict__ Af,
                                              const unsigned short* __restrict__ Wimg,
                                              unsigned short* __restrict__ C, int N,
                                              const float* __restrict__ scale,
                                              const float* __restrict__ shift, int mode) {
    __shared__ unsigned short Asw[64 * 128];    // 16KB
    __shared__ unsigned short Wt[128 * 128];    // 32KB
    int tid = threadIdx.x;
    int r0 = blockIdx.x * 64;

    // ---- stage Wt: straight 32KB copy of the precomputed swizzled image ----
    {
        const uint4* wi = reinterpret_cast<const uint4*>(Wimg);
        uint4* wl = reinterpret_cast<uint4*>(Wt);
        #pragma unroll
        for (int j = 0; j < 8; ++j)
            wl[tid + j * 256] = wi[tid + j * 256];
    }
    // ---- stage A tile (64 rows x 128 cols, bf16, swizzled) ----
    if (mode == 0) {
        const float* ap = &Af[(size_t)r0 * 128];
        #pragma unroll
        for (int j = 0; j < 4; ++j) {
            int u = tid + j * 256;               // 16B units [0,1024)
            int row = u >> 4, cg = u & 15;       // cols cg*8..cg*8+7
            unsigned short t8[8] = {0,0,0,0,0,0,0,0};
            if (r0 + row < N) {
                float4 a0 = *reinterpret_cast<const float4*>(ap + row * 128 + cg * 8);
                float4 a1 = *reinterpret_cast<const float4*>(ap + row * 128 + cg * 8 + 4);
                t8[0]=f2bf(a0.x); t8[1]=f2bf(a0.y); t8[2]=f2bf(a0.z); t8[3]=f2bf(a0.w);
                t8[4]=f2bf(a1.x); t8[5]=f2bf(a1.y); t8[6]=f2bf(a1.z); t8[7]=f2bf(a1.w);
            }
            int byte = (row * 256 + cg * 16) ^ ((row & 7) << 4);
            *reinterpret_cast<uint4*>(reinterpret_cast<char*>(Asw) + byte) =
                *reinterpret_cast<const uint4*>(t8);
        }
    } else {
        const unsigned short* ap = &Abf[(size_t)r0 * 128];
        #pragma unroll
        for (int j = 0; j < 4; ++j) {
            int u = tid + j * 256;
            int row = u >> 4, cg = u & 15;
            unsigned short t8[8] = {0,0,0,0,0,0,0,0};
            if (r0 + row < N) {
                ushort4 v0 = *reinterpret_cast<const ushort4*>(ap + (size_t)row * 128 + cg * 8);
                ushort4 v1 = *reinterpret_cast<const ushort4*>(ap + (size_t)row * 128 + cg * 8 + 4);
                float4 sc0 = *reinterpret_cast<const float4*>(&scale[cg * 8]);
                float4 sc1 = *reinterpret_cast<const float4*>(&scale[cg * 8 + 4]);
                float4 sf0 = *reinterpret_cast<const float4*>(&shift[cg * 8]);
                float4 sf1 = *reinterpret_cast<const float4*>(&shift[cg * 8 + 4]);
                t8[0] = f2bf(fmaxf(bf2f(v0.x) * sc0.x + sf0.x, 0.f));
                t8[1] = f2bf(fmaxf(bf2f(v0.y) * sc0.y + sf0.y, 0.f));
                t8[2] = f2bf(fmaxf(bf2f(v0.z) * sc0.z + sf0.z, 0.f));
                t8[3] = f2bf(fmaxf(bf2f(v0.w) * sc0.w + sf0.w, 0.f));
                t8[4] = f2bf(fmaxf(bf2f(v1.x) * sc1.x + sf1.x, 0.f));
                t8[5] = f2bf(fmaxf(bf2f(v1.y) * sc1.y + sf1.y, 0.f));
                t8[6] = f2bf(fmaxf(bf2f(v1.z) * sc1.z + sf1.z, 0.f));
                t8[7] = f2bf(fmaxf(bf2f(v1.w) * sc1.w + sf1.w, 0.f));
            }
            int byte = (row * 256 + cg * 16) ^ ((row & 7) << 4);
            *reinterpret_cast<uint4*>(reinterpret_cast<char*>(Asw) + byte) =
                *reinterpret_cast<const uint4*>(t8);
        }
    }
    __syncthreads();

    // ---- MFMA: wave wv -> rows wv*16..+15; frags: 1 (M) x 8 (N), K-loop 4x32 ----
    int wv = tid >> 6, lane = tid & 63;
    int lr = lane & 15, lk = lane >> 4;
    f32x4 acc[8] = {};
    #pragma unroll
    for (int kk = 0; kk < 4; ++kk) {
        int ar = wv * 16 + lr;
        int abyte = (ar * 256 + kk * 64 + lk * 16) ^ ((ar & 7) << 4);
        bf16x8 af = *reinterpret_cast<const bf16x8*>(reinterpret_cast<const char*>(Asw) + abyte);
        bf16x8 bf[8];
        #pragma unroll
        for (int nf = 0; nf < 8; ++nf) {
            int bn = nf * 16 + lr;
            int byte = (bn * 256 + kk * 64 + lk * 16) ^ ((bn & 7) << 4);
            bf[nf] = *reinterpret_cast<const bf16x8*>(reinterpret_cast<const char*>(Wt) + byte);
        }
        #pragma unroll
        for (int nf = 0; nf < 8; ++nf)
            acc[nf] = __builtin_amdgcn_mfma_f32_16x16x32_bf16(af, bf[nf], acc[nf], 0, 0, 0);
    }
    __syncthreads();     // all reads of Asw/Wt done -> reuse Asw as C bounce
    #pragma unroll
    for (int nf = 0; nf < 8; ++nf)
        #pragma unroll
        for (int r = 0; r < 4; ++r) {
            int row = wv * 16 + lk * 4 + r;
            int colc = nf * 16 + lr;
            Asw[row * 128 + colc] = f2bf(acc[nf][r]);
        }
    __syncthreads();
    #pragma unroll
    for (int j = 0; j < 4; ++j) {
        int u = tid + j * 256;
        int row = u >> 4, cg = u & 15;
        if (r0 + row < N)
            *reinterpret_cast<uint4*>(&C[((size_t)(r0 + row)) * 128 + cg * 8]) =
                *reinterpret_cast<const uint4*>(&Asw[row * 128 + cg * 8]);
    }
}

// ---------------- aggregation + fused BN-stats partials (round-6 proven; rs fold) ----------------

__global__ __launch_bounds__(256) void k_agg(const unsigned short* __restrict__ t, const uint2* __restrict__ colw,
                                             const int* __restrict__ rs, const int* __restrict__ blkoff,
                                             const int* __restrict__ deg,
                                             const float* __restrict__ dinv, const float* __restrict__ bias,
                                             unsigned short* __restrict__ out, int N,
                                             float* __restrict__ p1, float* __restrict__ p2) {
    __shared__ uint2 ec[4][64];
    __shared__ float sh[4][64][4];
    int wv = threadIdx.x >> 6, lane = threadIdx.x & 63;
    const ushort2* tp = reinterpret_cast<const ushort2*>(t);
    float b0 = bias[2 * lane], b1 = bias[2 * lane + 1];
    float s1x = 0.f, s1y = 0.f, s2x = 0.f, s2y = 0.f;
    for (int w = blockIdx.x * 4 + wv; w < N; w += gridDim.x * 4) {
        int start = rs[w] + blkoff[w >> 8];
        int cnt = deg[w];
        float di = dinv[w];
        float ax = 0.f, ay = 0.f;
        for (int base = 0; base < cnt; base += 64) {
            int m = min(cnt - base, 64);
            if (lane < m) ec[wv][lane] = colw[start + base + lane];
            asm volatile("s_waitcnt lgkmcnt(0)" ::: "memory");   // wave-private LDS visibility
            int e = 0;
            for (; e + 4 <= m; e += 4) {
                uint2 e0 = ec[wv][e], e1 = ec[wv][e + 1], e2 = ec[wv][e + 2], e3 = ec[wv][e + 3];
                ushort2 v0 = tp[(size_t)e0.x * 64 + lane];
                ushort2 v1 = tp[(size_t)e1.x * 64 + lane];
                ushort2 v2 = tp[(size_t)e2.x * 64 + lane];
                ushort2 v3 = tp[(size_t)e3.x * 64 + lane];
                float w0 = __builtin_bit_cast(float, e0.y), w1 = __builtin_bit_cast(float, e1.y);
                float w2 = __builtin_bit_cast(float, e2.y), w3 = __builtin_bit_cast(float, e3.y);
                ax += w0 * bf2f(v0.x) + w1 * bf2f(v1.x) + w2 * bf2f(v2.x) + w3 * bf2f(v3.x);
                ay += w0 * bf2f(v0.y) + w1 * bf2f(v1.y) + w2 * bf2f(v2.y) + w3 * bf2f(v3.y);
            }
            for (; e < m; ++e) {
                uint2 ee = ec[wv][e];
                ushort2 v = tp[(size_t)ee.x * 64 + lane];
                float ww = __builtin_bit_cast(float, ee.y);
                ax += ww * bf2f(v.x);
                ay += ww * bf2f(v.y);
            }
        }
        ushort2 self = tp[(size_t)w * 64 + lane];
        ushort2 o;
        o.x = f2bf(di * ax + di * di * bf2f(self.x) + b0);
        o.y = f2bf(di * ay + di * di * bf2f(self.y) + b1);
        reinterpret_cast<ushort2*>(out)[(size_t)w * 64 + lane] = o;
        float rx = bf2f(o.x), ry = bf2f(o.y);   // stats on STORED values (self-consistent BN)
        s1x += rx; s1y += ry; s2x += rx * rx; s2y += ry * ry;
    }
    sh[wv][lane][0] = s1x; sh[wv][lane][1] = s1y; sh[wv][lane][2] = s2x; sh[wv][lane][3] = s2y;
    __syncthreads();
    int tid = threadIdx.x;
    if (tid < 64) {
        float a0 = 0.f, a1 = 0.f, a2 = 0.f, a3 = 0.f;
        #pragma unroll
        for (int r = 0; r < 4; ++r) {
            a0 += sh[r][tid][0]; a1 += sh[r][tid][1];
            a2 += sh[r][tid][2]; a3 += sh[r][tid][3];
        }
        p1[(size_t)blockIdx.x * 128 + 2 * tid]     = a0;
        p1[(size_t)blockIdx.x * 128 + 2 * tid + 1] = a1;
        p2[(size_t)blockIdx.x * 128 + 2 * tid]     = a2;
        p2[(size_t)blockIdx.x * 128 + 2 * tid + 1] = a3;
    }
}

// ---------------- BN stats partial reductions (two-stage, proven) ----------------

__global__ __launch_bounds__(128) void k_statsmid(const float* __restrict__ p1, const float* __restrict__ p2,
                                                  int rows, float* __restrict__ pm1, float* __restrict__ pm2) {
    int c = threadIdx.x, b = blockIdx.x;
    int r0 = b * rows;
    float s1 = 0.f, s2 = 0.f;
    #pragma unroll 4
    for (int r = 0; r < rows; ++r) {
        s1 += p1[(size_t)(r0 + r) * 128 + c];
        s2 += p2[(size_t)(r0 + r) * 128 + c];
    }
    pm1[b * 128 + c] = s1;
    pm2[b * 128 + c] = s2;
}

__global__ __launch_bounds__(1024) void k_stats2(const float* __restrict__ p1, const float* __restrict__ p2,
                                                 int nb, int N,
                                                 const float* __restrict__ g, const float* __restrict__ be,
                                                 float* __restrict__ scale, float* __restrict__ shift) {
    __shared__ double sh1[1024], sh2[1024];
    int tid = threadIdx.x;
    int c = tid & 127, seg = tid >> 7;       // 8 segments
    double s1 = 0.0, s2 = 0.0;
    int b = seg;
    for (; b + 32 <= nb; b += 32) {
        double a0 = p1[(b      ) * 128 + c], q0 = p2[(b      ) * 128 + c];
        double a1 = p1[(b +  8) * 128 + c], q1 = p2[(b +  8) * 128 + c];
        double a2 = p1[(b + 16) * 128 + c], q2 = p2[(b + 16) * 128 + c];
        double a3 = p1[(b + 24) * 128 + c], q3 = p2[(b + 24) * 128 + c];
        s1 += (a0 + a1) + (a2 + a3);
        s2 += (q0 + q1) + (q2 + q3);
    }
    for (; b < nb; b += 8) { s1 += p1[b * 128 + c]; s2 += p2[b * 128 + c]; }
    sh1[tid] = s1; sh2[tid] = s2;
    __syncthreads();
    #pragma unroll
    for (int s = 4; s >= 1; s >>= 1) {
        if (seg < s) {
            sh1[tid] += sh1[tid + s * 128];
            sh2[tid] += sh2[tid + s * 128];
        }
        __syncthreads();
    }
    if (tid < 128) {
        double mu = sh1[c] / N;
        double var = sh2[c] / N - mu * mu;
        double inv = 1.0 / sqrt(var + (double)EPSBN);
        scale[c] = (float)((double)g[c] * inv);
        shift[c] = (float)((double)be[c] - mu * (double)g[c] * inv);
    }
}

// ---------------- pooling + fused output head (1024 blocks; last-block finalize) ----------------

__global__ __launch_bounds__(256) void k_pool(const unsigned short* __restrict__ h, const int* __restrict__ batch,
                                              const float* __restrict__ scale, const float* __restrict__ shift,
                                              const float* __restrict__ Wout, const float* __restrict__ bout,
                                              int N, int G, int nblocks,
                                              float* __restrict__ pool, int* __restrict__ cnt,
                                              int* __restrict__ done, float* __restrict__ outp) {
    __shared__ float pl[64];
    __shared__ int cl[64];
    __shared__ int lastFlag;
    int tid = threadIdx.x;
    if (tid < 64) { pl[tid] = 0.f; cl[tid] = 0; }
    __syncthreads();
    int wv = tid >> 6, lane = tid & 63;
    float sc0 = scale[2 * lane], sc1 = scale[2 * lane + 1];
    float sf0 = shift[2 * lane], sf1 = shift[2 * lane + 1];
    float w0 = Wout[2 * lane], w1 = Wout[2 * lane + 1];
    const ushort2* hp = reinterpret_cast<const ushort2*>(h);
    int wid = blockIdx.x * 4 + wv;
    int stride = gridDim.x * 4;
    for (int i = wid; i < N; i += stride * 4) {
        int i1 = i + stride, i2 = i + 2 * stride, i3 = i + 3 * stride;
        float s0 = 0.f, s1 = 0.f, s2 = 0.f, s3 = 0.f;
        {
            ushort2 v = hp[(size_t)i * 64 + lane];
            s0 = fmaxf(bf2f(v.x) * sc0 + sf0, 0.f) * w0 + fmaxf(bf2f(v.y) * sc1 + sf1, 0.f) * w1;
        }
        if (i1 < N) {
            ushort2 v = hp[(size_t)i1 * 64 + lane];
            s1 = fmaxf(bf2f(v.x) * sc0 + sf0, 0.f) * w0 + fmaxf(bf2f(v.y) * sc1 + sf1, 0.f) * w1;
        }
        if (i2 < N) {
            ushort2 v = hp[(size_t)i2 * 64 + lane];
            s2 = fmaxf(bf2f(v.x) * sc0 + sf0, 0.f) * w0 + fmaxf(bf2f(v.y) * sc1 + sf1, 0.f) * w1;
        }
        if (i3 < N) {
            ushort2 v = hp[(size_t)i3 * 64 + lane];
            s3 = fmaxf(bf2f(v.x) * sc0 + sf0, 0.f) * w0 + fmaxf(bf2f(v.y) * sc1 + sf1, 0.f) * w1;
        }
        #pragma unroll
        for (int o = 32; o > 0; o >>= 1) {
            s0 += __shfl_down(s0, o); s1 += __shfl_down(s1, o);
            s2 += __shfl_down(s2, o); s3 += __shfl_down(s3, o);
        }
        if (lane == 0) {
            atomicAdd(&pl[batch[i]], s0); atomicAdd(&cl[batch[i]], 1);
            if (i1 < N) { atomicAdd(&pl[batch[i1]], s1); atomicAdd(&cl[batch[i1]], 1); }
            if (i2 < N) { atomicAdd(&pl[batch[i2]], s2); atomicAdd(&cl[batch[i2]], 1); }
            if (i3 < N) { atomicAdd(&pl[batch[i3]], s3); atomicAdd(&cl[batch[i3]], 1); }
        }
    }
    __syncthreads();
    if (tid < 64) {
        atomicAdd(&pool[tid], pl[tid]);
        atomicAdd(&cnt[tid], cl[tid]);
    }
    __threadfence();
    if (tid == 0) {
        int old = atomicAdd(done, 1);
        lastFlag = (old == nblocks - 1);
    }
    __syncthreads();
    if (lastFlag && tid < G) {
        float pv = atomicAdd(&pool[tid], 0.f);   // device-scope coherent read
        int cv = atomicAdd(&cnt[tid], 0);
        float c = fmaxf((float)cv, 1.f);
        float p = pv / c + bout[0];
        outp[tid] = 1.f / (1.f + expf(-p));
    }
}

// ---------------- launch ----------------

extern "C" void kernel_launch(void* const* d_in, const int* in_sizes, int n_in,
                              void* d_out, int out_size, void* d_ws, size_t ws_size,
                              hipStream_t stream) {
    const float* x    = (const float*)d_in[0];
    const int*   ei   = (const int*)d_in[1];
    const int*   batch= (const int*)d_in[2];
    const float* W0p  = (const float*)d_in[3];
    const float* b0p  = (const float*)d_in[4];
    const float* g0p  = (const float*)d_in[5];
    const float* be0p = (const float*)d_in[6];
    const float* W1p  = (const float*)d_in[7];
    const float* b1p  = (const float*)d_in[8];
    const float* g1p  = (const float*)d_in[9];
    const float* be1p = (const float*)d_in[10];
    const float* W2p  = (const float*)d_in[11];
    const float* b2p  = (const float*)d_in[12];
    const float* g2p  = (const float*)d_in[13];
    const float* be2p = (const float*)d_in[14];
    const float* Woutp= (const float*)d_in[15];
    const float* boutp= (const float*)d_in[16];

    int N = in_sizes[0] / 128;
    int E = in_sizes[1] / 2;
    int G = out_size;
    const int* src = ei;
    const int* dst = ei + E;

    // bucket geometry: <=512 buckets, <=256 nodes each
    int shiftB = 7;
    while ((((N + (1 << shiftB) - 1) >> shiftB) > 512) && shiftB < 8) ++shiftB;
    int nbuck = (N + (1 << shiftB) - 1) >> shiftB;

    char* p = (char*)d_ws;
    auto alloc = [&](size_t bytes) {
        void* q = (void*)p;
        p += (bytes + 255) & ~(size_t)255;
        return q;
    };
    unsigned short* Bt  = (unsigned short*)alloc((size_t)N * 128 * 2);  // bf16 t (gemm out)
    unsigned short* Bh  = (unsigned short*)alloc((size_t)N * 128 * 2);  // bf16 h (agg out)
    uint2*  colw   = (uint2*) alloc((size_t)E * 8);
    uint2*  ebuf   = (uint2*) alloc((size_t)E * 8);
    int*    rsA    = (int*)   alloc((size_t)N * 4);
    float*  dinv   = (float*) alloc((size_t)N * 4);
    int*    blk    = (int*)   alloc(1024 * 4);
    int*    blkoff = (int*)   alloc(1024 * 4);
    int*    boff   = (int*)   alloc(512 * 4);
    unsigned short* Wimg = (unsigned short*)alloc(3 * 16384 * 2);
    float*  p1     = (float*) alloc((size_t)AGG_BLOCKS * 128 * 4);
    float*  p2     = (float*) alloc((size_t)AGG_BLOCKS * 128 * 4);
    float*  pm1    = (float*) alloc(128 * 128 * 4);
    float*  pm2    = (float*) alloc(128 * 128 * 4);
    float*  scale  = (float*) alloc(128 * 4);
    float*  shift  = (float*) alloc(128 * 4);
    // zero-init group: contiguous -> single memset
    char*   z0     = p;
    int*    deg    = (int*)   alloc((size_t)N * 4);
    int*    bcnt   = (int*)   alloc(512 * 4);
    int*    gcur   = (int*)   alloc(512 * 4);
    float*  pool   = (float*) alloc(64 * 4);
    int*    cnt    = (int*)   alloc(64 * 4);
    int*    done   = (int*)   alloc(256);
    size_t  zbytes = (size_t)(p - z0);

    hipMemsetAsync(z0, 0, zbytes, stream);

    int nb = (N + 255) / 256;
    k_prep    <<<259, 256, 0, stream>>>(W0p, W1p, W2p, Wimg, dst, E, deg, bcnt, shiftB);
    k_scan1   <<<nb, 256, 0, stream>>>(deg, N, rsA, blk, dinv);
    k_scan2x  <<<2, 1024, 0, stream>>>(blk, nb, blkoff, bcnt, 512, boff);
    k_bscatter<<<(E + 2047) / 2048, 256, 0, stream>>>(src, dst, E, boff, gcur, ebuf, shiftB);
    k_fill2   <<<nbuck, 256, 0, stream>>>(ebuf, bcnt, boff, rsA, blkoff, dinv, colw, shiftB);

    int gemmBlocks = (N + 63) / 64;
    int midRows = AGG_BLOCKS / 128;

    // layer 0
    k_gemm    <<<gemmBlocks, 256, 0, stream>>>(nullptr, x, Wimg, Bt, N, scale, shift, 0);
    k_agg     <<<AGG_BLOCKS, 256, 0, stream>>>(Bt, colw, rsA, blkoff, deg, dinv, b0p, Bh, N, p1, p2);
    k_statsmid<<<128, 128, 0, stream>>>(p1, p2, midRows, pm1, pm2);
    k_stats2  <<<1, 1024, 0, stream>>>(pm1, pm2, 128, N, g0p, be0p, scale, shift);
    // layer 1
    k_gemm    <<<gemmBlocks, 256, 0, stream>>>(Bh, nullptr, Wimg + 16384, Bt, N, scale, shift, 1);
    k_agg     <<<AGG_BLOCKS, 256, 0, stream>>>(Bt, colw, rsA, blkoff, deg, dinv, b1p, Bh, N, p1, p2);
    k_statsmid<<<128, 128, 0, stream>>>(p1, p2, midRows, pm1, pm2);
    k_stats2  <<<1, 1024, 0, stream>>>(pm1, pm2, 128, N, g1p, be1p, scale, shift);
    // layer 2
    k_gemm    <<<gemmBlocks, 256, 0, stream>>>(Bh, nullptr, Wimg + 32768, Bt, N, scale, shift, 1);
    k_agg     <<<AGG_BLOCKS, 256, 0, stream>>>(Bt, colw, rsA, blkoff, deg, dinv, b2p, Bh, N, p1, p2);
    k_statsmid<<<128, 128, 0, stream>>>(p1, p2, midRows, pm1, pm2);
    k_stats2  <<<1, 1024, 0, stream>>>(pm1, pm2, 128, N, g2p, be2p, scale, shift);
    // head (pool + finalize fused)
    k_pool <<<1024, 256, 0, stream>>>(Bh, batch, scale, shift, Woutp, boutp, N, G, 1024, pool, cnt, done, (float*)d_out);
}

// Round 12
// 287.305 us; speedup vs baseline: 1.1267x; 1.1267x over previous
//
#include <hip/hip_runtime.h>

#define EPSBN 1e-5f
#define AGG_BLOCKS 4096

using bf16x8 = __attribute__((ext_vector_type(8))) short;
using f32x4  = __attribute__((ext_vector_type(4))) float;

__device__ __forceinline__ unsigned short f2bf(float f) {
    unsigned u = __builtin_bit_cast(unsigned, f);
    unsigned r = (u + 0x7FFFu + ((u >> 16) & 1u)) >> 16;   // RTNE
    return (unsigned short)r;
}
__device__ __forceinline__ float bf2f(unsigned short s) {
    unsigned u = ((unsigned)s) << 16;
    return __builtin_bit_cast(float, u);
}

// ---------------- fused prep: W images (blocks 0-2) + degree/bucket hist (blocks 3+) ----------------

__global__ __launch_bounds__(256) void k_prep(const float* __restrict__ W0, const float* __restrict__ W1,
                                              const float* __restrict__ W2, unsigned short* __restrict__ Wimg,
                                              const int* __restrict__ dst, int E,
                                              int* __restrict__ deg, int* __restrict__ bcnt, int shift) {
    int tid = threadIdx.x;
    if (blockIdx.x < 3) {
        const float* W = (blockIdx.x == 0) ? W0 : (blockIdx.x == 1) ? W1 : W2;
        unsigned short* out = Wimg + (size_t)blockIdx.x * 16384;
        int n = tid & 127, kh = tid >> 7;
        const float* wp = &W[(kh * 64) * 128 + n];
        #pragma unroll
        for (int kb = 0; kb < 8; ++kb) {
            unsigned short t8[8];
            #pragma unroll
            for (int e = 0; e < 8; ++e)
                t8[e] = f2bf(wp[(kb * 8 + e) * 128]);
            int byte = (n * 256 + kh * 128 + kb * 16) ^ ((n & 7) << 4);
            *reinterpret_cast<uint4*>(reinterpret_cast<char*>(out) + byte) =
                *reinterpret_cast<const uint4*>(t8);
        }
        return;
    }
    __shared__ int lh[512];
    for (int i = tid; i < 512; i += 256) lh[i] = 0;
    __syncthreads();
    int b = blockIdx.x - 3;                      // 256 hist blocks
    for (int i = b * 256 + tid; i < E; i += 256 * 256) {
        int d = dst[i];
        atomicAdd(&deg[d], 1);
        atomicAdd(&lh[d >> shift], 1);
    }
    __syncthreads();
    for (int i = tid; i < 512; i += 256)
        if (lh[i]) atomicAdd(&bcnt[i], lh[i]);
}

// scan1 also emits dinv (deg already in hand)
__global__ void k_scan1(const int* __restrict__ deg, int N, int* __restrict__ rs, int* __restrict__ blk,
                        float* __restrict__ dinv) {
    __shared__ int sh[256];
    int tid = threadIdx.x;
    int i = blockIdx.x * 256 + tid;
    int v = (i < N) ? deg[i] : 0;
    if (i < N) dinv[i] = rsqrtf((float)(v + 1));     // +1 self-loop
    sh[tid] = v; __syncthreads();
    for (int off = 1; off < 256; off <<= 1) {
        int t = (tid >= off) ? sh[tid - off] : 0;
        __syncthreads();
        sh[tid] += t;
        __syncthreads();
    }
    if (i < N) rs[i] = sh[tid] - v;          // block-local exclusive
    if (tid == 255) blk[blockIdx.x] = sh[255];
}

// two independent exclusive scans in one dispatch
__global__ __launch_bounds__(1024) void k_scan2x(const int* __restrict__ blk, int nb, int* __restrict__ blkoff,
                                                 const int* __restrict__ bcnt, int nb2, int* __restrict__ boff) {
    __shared__ int sh[1024];
    const int* in = blockIdx.x ? bcnt : blk;
    int n = blockIdx.x ? nb2 : nb;
    int* outp = blockIdx.x ? boff : blkoff;
    int tid = threadIdx.x;
    int v = (tid < n) ? in[tid] : 0;
    sh[tid] = v; __syncthreads();
    for (int off = 1; off < 1024; off <<= 1) {
        int t = (tid >= off) ? sh[tid - off] : 0;
        __syncthreads();
        sh[tid] += t;
        __syncthreads();
    }
    if (tid < n) outp[tid] = sh[tid] - v; // exclusive
}

// ---------------- bucketed edge scatter ----------------

__global__ __launch_bounds__(256) void k_bscatter(const int* __restrict__ src, const int* __restrict__ dst, int E,
                                                  const int* __restrict__ boff, int* __restrict__ gcur,
                                                  uint2* __restrict__ ebuf, int shift) {
    __shared__ int lh[512], lb[512];
    int tid = threadIdx.x;
    int base = blockIdx.x * 2048;
    for (int i = tid; i < 512; i += 256) lh[i] = 0;
    __syncthreads();
    int ms[8], md[8];
    #pragma unroll
    for (int j = 0; j < 8; ++j) {
        int idx = base + j * 256 + tid;
        if (idx < E) {
            ms[j] = src[idx]; md[j] = dst[idx];
            atomicAdd(&lh[md[j] >> shift], 1);
        } else md[j] = -1;
    }
    __syncthreads();
    for (int b = tid; b < 512; b += 256) {
        int c = lh[b];
        lb[b] = c ? atomicAdd(&gcur[b], c) : 0;
    }
    __syncthreads();
    for (int i = tid; i < 512; i += 256) lh[i] = 0;
    __syncthreads();
    #pragma unroll
    for (int j = 0; j < 8; ++j) {
        if (md[j] >= 0) {
            int b = md[j] >> shift;
            int r = atomicAdd(&lh[b], 1);
            ebuf[boff[b] + lb[b] + r] = make_uint2((unsigned)ms[j], (unsigned)md[j]);
        }
    }
}

// ---------------- CSR fill: colw[pos] = (src, dinv[src]); rs fold of blkoff ----------------

__global__ __launch_bounds__(256) void k_fill2(const uint2* __restrict__ ebuf, const int* __restrict__ bcnt,
                                               const int* __restrict__ boff, const int* __restrict__ rs,
                                               const int* __restrict__ blkoff, const float* __restrict__ dinv,
                                               uint2* __restrict__ colw, int shift) {
    __shared__ int lcur[256];
    int b = blockIdx.x;
    int n0 = b << shift;
    int cnt = bcnt[b], s = boff[b];
    int span = 1 << shift;
    for (int i = threadIdx.x; i < span; i += 256) lcur[i] = 0;
    __syncthreads();
    for (int i = threadIdx.x; i < cnt; i += 256) {
        uint2 e = ebuf[s + i];
        int d = (int)e.y;
        int sv = (int)e.x;
        int pos = rs[d] + blkoff[d >> 8] + atomicAdd(&lcur[d - n0], 1);
        colw[pos] = make_uint2((unsigned)sv, __builtin_bit_cast(unsigned, dinv[sv]));
    }
}

// ---------------- MFMA GEMM: 64-row tiles (782 blocks, 48KB LDS) — round-6 proven ----------------

__global__ __launch_bounds__(256) void k_gemm(const unsigned short* __restrict__ Abf,
                                              const float* __restrict__ Af,
                                              const unsigned short* __restrict__ Wimg,
                                              unsigned short* __restrict__ C, int N,
                                              const float* __restrict__ scale,
                                              const float* __restrict__ shift, int mode) {
    __shared__ unsigned short Asw[64 * 128];    // 16KB
    __shared__ unsigned short Wt[128 * 128];    // 32KB
    int tid = threadIdx.x;
    int r0 = blockIdx.x * 64;

    // ---- stage Wt: straight 32KB copy of the precomputed swizzled image ----
    {
        const uint4* wi = reinterpret_cast<const uint4*>(Wimg);
        uint4* wl = reinterpret_cast<uint4*>(Wt);
        #pragma unroll
        for (int j = 0; j < 8; ++j)
            wl[tid + j * 256] = wi[tid + j * 256];
    }
    // ---- stage A tile (64 rows x 128 cols, bf16, swizzled) ----
    if (mode == 0) {
        const float* ap = &Af[(size_t)r0 * 128];
        #pragma unroll
        for (int j = 0; j < 4; ++j) {
            int u = tid + j * 256;               // 16B units [0,1024)
            int row = u >> 4, cg = u & 15;       // cols cg*8..cg*8+7
            unsigned short t8[8] = {0,0,0,0,0,0,0,0};
            if (r0 + row < N) {
                float4 a0 = *reinterpret_cast<const float4*>(ap + row * 128 + cg * 8);
                float4 a1 = *reinterpret_cast<const float4*>(ap + row * 128 + cg * 8 + 4);
                t8[0]=f2bf(a0.x); t8[1]=f2bf(a0.y); t8[2]=f2bf(a0.z); t8[3]=f2bf(a0.w);
                t8[4]=f2bf(a1.x); t8[5]=f2bf(a1.y); t8[6]=f2bf(a1.z); t8[7]=f2bf(a1.w);
            }
            int byte = (row * 256 + cg * 16) ^ ((row & 7) << 4);
            *reinterpret_cast<uint4*>(reinterpret_cast<char*>(Asw) + byte) =
                *reinterpret_cast<const uint4*>(t8);
        }
    } else {
        const unsigned short* ap = &Abf[(size_t)r0 * 128];
        #pragma unroll
        for (int j = 0; j < 4; ++j) {
            int u = tid + j * 256;
            int row = u >> 4, cg = u & 15;
            unsigned short t8[8] = {0,0,0,0,0,0,0,0};
            if (r0 + row < N) {
                ushort4 v0 = *reinterpret_cast<const ushort4*>(ap + (size_t)row * 128 + cg * 8);
                ushort4 v1 = *reinterpret_cast<const ushort4*>(ap + (size_t)row * 128 + cg * 8 + 4);
                float4 sc0 = *reinterpret_cast<const float4*>(&scale[cg * 8]);
                float4 sc1 = *reinterpret_cast<const float4*>(&scale[cg * 8 + 4]);
                float4 sf0 = *reinterpret_cast<const float4*>(&shift[cg * 8]);
                float4 sf1 = *reinterpret_cast<const float4*>(&shift[cg * 8 + 4]);
                t8[0] = f2bf(fmaxf(bf2f(v0.x) * sc0.x + sf0.x, 0.f));
                t8[1] = f2bf(fmaxf(bf2f(v0.y) * sc0.y + sf0.y, 0.f));
                t8[2] = f2bf(fmaxf(bf2f(v0.z) * sc0.z + sf0.z, 0.f));
                t8[3] = f2bf(fmaxf(bf2f(v0.w) * sc0.w + sf0.w, 0.f));
                t8[4] = f2bf(fmaxf(bf2f(v1.x) * sc1.x + sf1.x, 0.f));
                t8[5] = f2bf(fmaxf(bf2f(v1.y) * sc1.y + sf1.y, 0.f));
                t8[6] = f2bf(fmaxf(bf2f(v1.z) * sc1.z + sf1.z, 0.f));
                t8[7] = f2bf(fmaxf(bf2f(v1.w) * sc1.w + sf1.w, 0.f));
            }
            int byte = (row * 256 + cg * 16) ^ ((row & 7) << 4);
            *reinterpret_cast<uint4*>(reinterpret_cast<char*>(Asw) + byte) =
                *reinterpret_cast<const uint4*>(t8);
        }
    }
    __syncthreads();

    // ---- MFMA: wave wv -> rows wv*16..+15; frags: 1 (M) x 8 (N), K-loop 4x32 ----
    int wv = tid >> 6, lane = tid & 63;
    int lr = lane & 15, lk = lane >> 4;
    f32x4 acc[8] = {};
    #pragma unroll
    for (int kk = 0; kk < 4; ++kk) {
        int ar = wv * 16 + lr;
        int abyte = (ar * 256 + kk * 64 + lk * 16) ^ ((ar & 7) << 4);
        bf16x8 af = *reinterpret_cast<const bf16x8*>(reinterpret_cast<const char*>(Asw) + abyte);
        bf16x8 bf[8];
        #pragma unroll
        for (int nf = 0; nf < 8; ++nf) {
            int bn = nf * 16 + lr;
            int byte = (bn * 256 + kk * 64 + lk * 16) ^ ((bn & 7) << 4);
            bf[nf] = *reinterpret_cast<const bf16x8*>(reinterpret_cast<const char*>(Wt) + byte);
        }
        #pragma unroll
        for (int nf = 0; nf < 8; ++nf)
            acc[nf] = __builtin_amdgcn_mfma_f32_16x16x32_bf16(af, bf[nf], acc[nf], 0, 0, 0);
    }
    __syncthreads();     // all reads of Asw/Wt done -> reuse Asw as C bounce
    #pragma unroll
    for (int nf = 0; nf < 8; ++nf)
        #pragma unroll
        for (int r = 0; r < 4; ++r) {
            int row = wv * 16 + lk * 4 + r;
            int colc = nf * 16 + lr;
            Asw[row * 128 + colc] = f2bf(acc[nf][r]);
        }
    __syncthreads();
    #pragma unroll
    for (int j = 0; j < 4; ++j) {
        int u = tid + j * 256;
        int row = u >> 4, cg = u & 15;
        if (r0 + row < N)
            *reinterpret_cast<uint4*>(&C[((size_t)(r0 + row)) * 128 + cg * 8]) =
                *reinterpret_cast<const uint4*>(&Asw[row * 128 + cg * 8]);
    }
}

// ---------------- aggregation + fused BN-stats partials (round-6 proven; rs fold) ----------------

__global__ __launch_bounds__(256) void k_agg(const unsigned short* __restrict__ t, const uint2* __restrict__ colw,
                                             const int* __restrict__ rs, const int* __restrict__ blkoff,
                                             const int* __restrict__ deg,
                                             const float* __restrict__ dinv, const float* __restrict__ bias,
                                             unsigned short* __restrict__ out, int N,
                                             float* __restrict__ p1, float* __restrict__ p2) {
    __shared__ uint2 ec[4][64];
    __shared__ float sh[4][64][4];
    int wv = threadIdx.x >> 6, lane = threadIdx.x & 63;
    const ushort2* tp = reinterpret_cast<const ushort2*>(t);
    float b0 = bias[2 * lane], b1 = bias[2 * lane + 1];
    float s1x = 0.f, s1y = 0.f, s2x = 0.f, s2y = 0.f;
    for (int w = blockIdx.x * 4 + wv; w < N; w += gridDim.x * 4) {
        int start = rs[w] + blkoff[w >> 8];
        int cnt = deg[w];
        float di = dinv[w];
        float ax = 0.f, ay = 0.f;
        for (int base = 0; base < cnt; base += 64) {
            int m = min(cnt - base, 64);
            if (lane < m) ec[wv][lane] = colw[start + base + lane];
            asm volatile("s_waitcnt lgkmcnt(0)" ::: "memory");   // wave-private LDS visibility
            int e = 0;
            for (; e + 4 <= m; e += 4) {
                uint2 e0 = ec[wv][e], e1 = ec[wv][e + 1], e2 = ec[wv][e + 2], e3 = ec[wv][e + 3];
                ushort2 v0 = tp[(size_t)e0.x * 64 + lane];
                ushort2 v1 = tp[(size_t)e1.x * 64 + lane];
                ushort2 v2 = tp[(size_t)e2.x * 64 + lane];
                ushort2 v3 = tp[(size_t)e3.x * 64 + lane];
                float w0 = __builtin_bit_cast(float, e0.y), w1 = __builtin_bit_cast(float, e1.y);
                float w2 = __builtin_bit_cast(float, e2.y), w3 = __builtin_bit_cast(float, e3.y);
                ax += w0 * bf2f(v0.x) + w1 * bf2f(v1.x) + w2 * bf2f(v2.x) + w3 * bf2f(v3.x);
                ay += w0 * bf2f(v0.y) + w1 * bf2f(v1.y) + w2 * bf2f(v2.y) + w3 * bf2f(v3.y);
            }
            for (; e < m; ++e) {
                uint2 ee = ec[wv][e];
                ushort2 v = tp[(size_t)ee.x * 64 + lane];
                float ww = __builtin_bit_cast(float, ee.y);
                ax += ww * bf2f(v.x);
                ay += ww * bf2f(v.y);
            }
        }
        ushort2 self = tp[(size_t)w * 64 + lane];
        ushort2 o;
        o.x = f2bf(di * ax + di * di * bf2f(self.x) + b0);
        o.y = f2bf(di * ay + di * di * bf2f(self.y) + b1);
        reinterpret_cast<ushort2*>(out)[(size_t)w * 64 + lane] = o;
        float rx = bf2f(o.x), ry = bf2f(o.y);   // stats on STORED values (self-consistent BN)
        s1x += rx; s1y += ry; s2x += rx * rx; s2y += ry * ry;
    }
    sh[wv][lane][0] = s1x; sh[wv][lane][1] = s1y; sh[wv][lane][2] = s2x; sh[wv][lane][3] = s2y;
    __syncthreads();
    int tid = threadIdx.x;
    if (tid < 64) {
        float a0 = 0.f, a1 = 0.f, a2 = 0.f, a3 = 0.f;
        #pragma unroll
        for (int r = 0; r < 4; ++r) {
            a0 += sh[r][tid][0]; a1 += sh[r][tid][1];
            a2 += sh[r][tid][2]; a3 += sh[r][tid][3];
        }
        p1[(size_t)blockIdx.x * 128 + 2 * tid]     = a0;
        p1[(size_t)blockIdx.x * 128 + 2 * tid + 1] = a1;
        p2[(size_t)blockIdx.x * 128 + 2 * tid]     = a2;
        p2[(size_t)blockIdx.x * 128 + 2 * tid + 1] = a3;
    }
}

// ---------------- BN stats partial reductions (two-stage, proven) ----------------

__global__ __launch_bounds__(128) void k_statsmid(const float* __restrict__ p1, const float* __restrict__ p2,
                                                  int rows, float* __restrict__ pm1, float* __restrict__ pm2) {
    int c = threadIdx.x, b = blockIdx.x;
    int r0 = b * rows;
    float s1 = 0.f, s2 = 0.f;
    #pragma unroll 4
    for (int r = 0; r < rows; ++r) {
        s1 += p1[(size_t)(r0 + r) * 128 + c];
        s2 += p2[(size_t)(r0 + r) * 128 + c];
    }
    pm1[b * 128 + c] = s1;
    pm2[b * 128 + c] = s2;
}

__global__ __launch_bounds__(1024) void k_stats2(const float* __restrict__ p1, const float* __restrict__ p2,
                                                 int nb, int N,
                                                 const float* __restrict__ g, const float* __restrict__ be,
                                                 float* __restrict__ scale, float* __restrict__ shift) {
    __shared__ double sh1[1024], sh2[1024];
    int tid = threadIdx.x;
    int c = tid & 127, seg = tid >> 7;       // 8 segments
    double s1 = 0.0, s2 = 0.0;
    int b = seg;
    for (; b + 32 <= nb; b += 32) {
        double a0 = p1[(b      ) * 128 + c], q0 = p2[(b      ) * 128 + c];
        double a1 = p1[(b +  8) * 128 + c], q1 = p2[(b +  8) * 128 + c];
        double a2 = p1[(b + 16) * 128 + c], q2 = p2[(b + 16) * 128 + c];
        double a3 = p1[(b + 24) * 128 + c], q3 = p2[(b + 24) * 128 + c];
        s1 += (a0 + a1) + (a2 + a3);
        s2 += (q0 + q1) + (q2 + q3);
    }
    for (; b < nb; b += 8) { s1 += p1[b * 128 + c]; s2 += p2[b * 128 + c]; }
    sh1[tid] = s1; sh2[tid] = s2;
    __syncthreads();
    #pragma unroll
    for (int s = 4; s >= 1; s >>= 1) {
        if (seg < s) {
            sh1[tid] += sh1[tid + s * 128];
            sh2[tid] += sh2[tid + s * 128];
        }
        __syncthreads();
    }
    if (tid < 128) {
        double mu = sh1[c] / N;
        double var = sh2[c] / N - mu * mu;
        double inv = 1.0 / sqrt(var + (double)EPSBN);
        scale[c] = (float)((double)g[c] * inv);
        shift[c] = (float)((double)be[c] - mu * (double)g[c] * inv);
    }
}

// ---------------- pooling + output head (split form — round-10 proven) ----------------

__global__ __launch_bounds__(256) void k_pool(const unsigned short* __restrict__ h, const int* __restrict__ batch,
                                              const float* __restrict__ scale, const float* __restrict__ shift,
                                              const float* __restrict__ Wout, int N, int G,
                                              float* __restrict__ pool, int* __restrict__ cnt) {
    __shared__ float pl[64];
    __shared__ int cl[64];
    int tid = threadIdx.x;
    if (tid < 64) { pl[tid] = 0.f; cl[tid] = 0; }
    __syncthreads();
    int wv = tid >> 6, lane = tid & 63;
    float sc0 = scale[2 * lane], sc1 = scale[2 * lane + 1];
    float sf0 = shift[2 * lane], sf1 = shift[2 * lane + 1];
    float w0 = Wout[2 * lane], w1 = Wout[2 * lane + 1];
    const ushort2* hp = reinterpret_cast<const ushort2*>(h);
    int wid = blockIdx.x * 4 + wv;
    int stride = gridDim.x * 4;
    for (int i = wid; i < N; i += stride * 4) {
        int i1 = i + stride, i2 = i + 2 * stride, i3 = i + 3 * stride;
        float s0 = 0.f, s1 = 0.f, s2 = 0.f, s3 = 0.f;
        {
            ushort2 v = hp[(size_t)i * 64 + lane];
            s0 = fmaxf(bf2f(v.x) * sc0 + sf0, 0.f) * w0 + fmaxf(bf2f(v.y) * sc1 + sf1, 0.f) * w1;
        }
        if (i1 < N) {
            ushort2 v = hp[(size_t)i1 * 64 + lane];
            s1 = fmaxf(bf2f(v.x) * sc0 + sf0, 0.f) * w0 + fmaxf(bf2f(v.y) * sc1 + sf1, 0.f) * w1;
        }
        if (i2 < N) {
            ushort2 v = hp[(size_t)i2 * 64 + lane];
            s2 = fmaxf(bf2f(v.x) * sc0 + sf0, 0.f) * w0 + fmaxf(bf2f(v.y) * sc1 + sf1, 0.f) * w1;
        }
        if (i3 < N) {
            ushort2 v = hp[(size_t)i3 * 64 + lane];
            s3 = fmaxf(bf2f(v.x) * sc0 + sf0, 0.f) * w0 + fmaxf(bf2f(v.y) * sc1 + sf1, 0.f) * w1;
        }
        #pragma unroll
        for (int o = 32; o > 0; o >>= 1) {
            s0 += __shfl_down(s0, o); s1 += __shfl_down(s1, o);
            s2 += __shfl_down(s2, o); s3 += __shfl_down(s3, o);
        }
        if (lane == 0) {
            atomicAdd(&pl[batch[i]], s0); atomicAdd(&cl[batch[i]], 1);
            if (i1 < N) { atomicAdd(&pl[batch[i1]], s1); atomicAdd(&cl[batch[i1]], 1); }
            if (i2 < N) { atomicAdd(&pl[batch[i2]], s2); atomicAdd(&cl[batch[i2]], 1); }
            if (i3 < N) { atomicAdd(&pl[batch[i3]], s3); atomicAdd(&cl[batch[i3]], 1); }
        }
    }
    __syncthreads();
    if (tid < 64) {
        atomicAdd(&pool[tid], pl[tid]);
        atomicAdd(&cnt[tid], cl[tid]);
    }
}

__global__ void k_final(const float* __restrict__ pool, const int* __restrict__ cnt,
                        const float* __restrict__ bout, int G, float* __restrict__ out) {
    int g = blockIdx.x * blockDim.x + threadIdx.x;
    if (g < G) {
        float c = fmaxf((float)cnt[g], 1.f);
        float p = pool[g] / c + bout[0];
        out[g] = 1.f / (1.f + expf(-p));
    }
}

// ---------------- launch ----------------

extern "C" void kernel_launch(void* const* d_in, const int* in_sizes, int n_in,
                              void* d_out, int out_size, void* d_ws, size_t ws_size,
                              hipStream_t stream) {
    const float* x    = (const float*)d_in[0];
    const int*   ei   = (const int*)d_in[1];
    const int*   batch= (const int*)d_in[2];
    const float* W0p  = (const float*)d_in[3];
    const float* b0p  = (const float*)d_in[4];
    const float* g0p  = (const float*)d_in[5];
    const float* be0p = (const float*)d_in[6];
    const float* W1p  = (const float*)d_in[7];
    const float* b1p  = (const float*)d_in[8];
    const float* g1p  = (const float*)d_in[9];
    const float* be1p = (const float*)d_in[10];
    const float* W2p  = (const float*)d_in[11];
    const float* b2p  = (const float*)d_in[12];
    const float* g2p  = (const float*)d_in[13];
    const float* be2p = (const float*)d_in[14];
    const float* Woutp= (const float*)d_in[15];
    const float* boutp= (const float*)d_in[16];

    int N = in_sizes[0] / 128;
    int E = in_sizes[1] / 2;
    int G = out_size;
    const int* src = ei;
    const int* dst = ei + E;

    // bucket geometry: <=512 buckets, <=256 nodes each
    int shiftB = 7;
    while ((((N + (1 << shiftB) - 1) >> shiftB) > 512) && shiftB < 8) ++shiftB;
    int nbuck = (N + (1 << shiftB) - 1) >> shiftB;

    char* p = (char*)d_ws;
    auto alloc = [&](size_t bytes) {
        void* q = (void*)p;
        p += (bytes + 255) & ~(size_t)255;
        return q;
    };
    unsigned short* Bt  = (unsigned short*)alloc((size_t)N * 128 * 2);  // bf16 t (gemm out)
    unsigned short* Bh  = (unsigned short*)alloc((size_t)N * 128 * 2);  // bf16 h (agg out)
    uint2*  colw   = (uint2*) alloc((size_t)E * 8);
    uint2*  ebuf   = (uint2*) alloc((size_t)E * 8);
    int*    rsA    = (int*)   alloc((size_t)N * 4);
    float*  dinv   = (float*) alloc((size_t)N * 4);
    int*    blk    = (int*)   alloc(1024 * 4);
    int*    blkoff = (int*)   alloc(1024 * 4);
    int*    boff   = (int*)   alloc(512 * 4);
    unsigned short* Wimg = (unsigned short*)alloc(3 * 16384 * 2);
    float*  p1     = (float*) alloc((size_t)AGG_BLOCKS * 128 * 4);
    float*  p2     = (float*) alloc((size_t)AGG_BLOCKS * 128 * 4);
    float*  pm1    = (float*) alloc(128 * 128 * 4);
    float*  pm2    = (float*) alloc(128 * 128 * 4);
    float*  scale  = (float*) alloc(128 * 4);
    float*  shift  = (float*) alloc(128 * 4);
    // zero-init group: contiguous -> single memset
    char*   z0     = p;
    int*    deg    = (int*)   alloc((size_t)N * 4);
    int*    bcnt   = (int*)   alloc(512 * 4);
    int*    gcur   = (int*)   alloc(512 * 4);
    float*  pool   = (float*) alloc(64 * 4);
    int*    cnt    = (int*)   alloc(64 * 4);
    size_t  zbytes = (size_t)(p - z0);

    hipMemsetAsync(z0, 0, zbytes, stream);

    int nb = (N + 255) / 256;
    k_prep    <<<259, 256, 0, stream>>>(W0p, W1p, W2p, Wimg, dst, E, deg, bcnt, shiftB);
    k_scan1   <<<nb, 256, 0, stream>>>(deg, N, rsA, blk, dinv);
    k_scan2x  <<<2, 1024, 0, stream>>>(blk, nb, blkoff, bcnt, 512, boff);
    k_bscatter<<<(E + 2047) / 2048, 256, 0, stream>>>(src, dst, E, boff, gcur, ebuf, shiftB);
    k_fill2   <<<nbuck, 256, 0, stream>>>(ebuf, bcnt, boff, rsA, blkoff, dinv, colw, shiftB);

    int gemmBlocks = (N + 63) / 64;
    int midRows = AGG_BLOCKS / 128;

    // layer 0
    k_gemm    <<<gemmBlocks, 256, 0, stream>>>(nullptr, x, Wimg, Bt, N, scale, shift, 0);
    k_agg     <<<AGG_BLOCKS, 256, 0, stream>>>(Bt, colw, rsA, blkoff, deg, dinv, b0p, Bh, N, p1, p2);
    k_statsmid<<<128, 128, 0, stream>>>(p1, p2, midRows, pm1, pm2);
    k_stats2  <<<1, 1024, 0, stream>>>(pm1, pm2, 128, N, g0p, be0p, scale, shift);
    // layer 1
    k_gemm    <<<gemmBlocks, 256, 0, stream>>>(Bh, nullptr, Wimg + 16384, Bt, N, scale, shift, 1);
    k_agg     <<<AGG_BLOCKS, 256, 0, stream>>>(Bt, colw, rsA, blkoff, deg, dinv, b1p, Bh, N, p1, p2);
    k_statsmid<<<128, 128, 0, stream>>>(p1, p2, midRows, pm1, pm2);
    k_stats2  <<<1, 1024, 0, stream>>>(pm1, pm2, 128, N, g1p, be1p, scale, shift);
    // layer 2
    k_gemm    <<<gemmBlocks, 256, 0, stream>>>(Bh, nullptr, Wimg + 32768, Bt, N, scale, shift, 1);
    k_agg     <<<AGG_BLOCKS, 256, 0, stream>>>(Bt, colw, rsA, blkoff, deg, dinv, b2p, Bh, N, p1, p2);
    k_statsmid<<<128, 128, 0, stream>>>(p1, p2, midRows, pm1, pm2);
    k_stats2  <<<1, 1024, 0, stream>>>(pm1, pm2, 128, N, g2p, be2p, scale, shift);
    // head
    k_pool <<<1024, 256, 0, stream>>>(Bh, batch, scale, shift, Woutp, N, G, pool, cnt);
    k_final<<<1, 64, 0, stream>>>(pool, cnt, boutp, G, (float*)d_out);
}

// Round 13
// 277.562 us; speedup vs baseline: 1.1663x; 1.0351x over previous
//
#include <hip/hip_runtime.h>

#define EPSBN 1e-5f
#define AGG_BLOCKS 2048

using bf16x8 = __attribute__((ext_vector_type(8))) short;
using f32x4  = __attribute__((ext_vector_type(4))) float;

__device__ __forceinline__ unsigned short f2bf(float f) {
    unsigned u = __builtin_bit_cast(unsigned, f);
    unsigned r = (u + 0x7FFFu + ((u >> 16) & 1u)) >> 16;   // RTNE
    return (unsigned short)r;
}
__device__ __forceinline__ float bf2f(unsigned short s) {
    unsigned u = ((unsigned)s) << 16;
    return __builtin_bit_cast(float, u);
}

// ---------------- fused prep: W images (blocks 0-2) + degree/bucket hist (blocks 3+) ----------------

__global__ __launch_bounds__(256) void k_prep(const float* __restrict__ W0, const float* __restrict__ W1,
                                              const float* __restrict__ W2, unsigned short* __restrict__ Wimg,
                                              const int* __restrict__ dst, int E,
                                              int* __restrict__ deg, int* __restrict__ bcnt, int shift) {
    int tid = threadIdx.x;
    if (blockIdx.x < 3) {
        const float* W = (blockIdx.x == 0) ? W0 : (blockIdx.x == 1) ? W1 : W2;
        unsigned short* out = Wimg + (size_t)blockIdx.x * 16384;
        int n = tid & 127, kh = tid >> 7;
        const float* wp = &W[(kh * 64) * 128 + n];
        #pragma unroll
        for (int kb = 0; kb < 8; ++kb) {
            unsigned short t8[8];
            #pragma unroll
            for (int e = 0; e < 8; ++e)
                t8[e] = f2bf(wp[(kb * 8 + e) * 128]);
            int byte = (n * 256 + kh * 128 + kb * 16) ^ ((n & 7) << 4);
            *reinterpret_cast<uint4*>(reinterpret_cast<char*>(out) + byte) =
                *reinterpret_cast<const uint4*>(t8);
        }
        return;
    }
    __shared__ int lh[512];
    for (int i = tid; i < 512; i += 256) lh[i] = 0;
    __syncthreads();
    int b = blockIdx.x - 3;                      // 256 hist blocks
    for (int i = b * 256 + tid; i < E; i += 256 * 256) {
        int d = dst[i];
        atomicAdd(&deg[d], 1);
        atomicAdd(&lh[d >> shift], 1);
    }
    __syncthreads();
    for (int i = tid; i < 512; i += 256)
        if (lh[i]) atomicAdd(&bcnt[i], lh[i]);
}

// scan1 also emits dinv (deg already in hand)
__global__ void k_scan1(const int* __restrict__ deg, int N, int* __restrict__ rs, int* __restrict__ blk,
                        float* __restrict__ dinv) {
    __shared__ int sh[256];
    int tid = threadIdx.x;
    int i = blockIdx.x * 256 + tid;
    int v = (i < N) ? deg[i] : 0;
    if (i < N) dinv[i] = rsqrtf((float)(v + 1));     // +1 self-loop
    sh[tid] = v; __syncthreads();
    for (int off = 1; off < 256; off <<= 1) {
        int t = (tid >= off) ? sh[tid - off] : 0;
        __syncthreads();
        sh[tid] += t;
        __syncthreads();
    }
    if (i < N) rs[i] = sh[tid] - v;          // block-local exclusive
    if (tid == 255) blk[blockIdx.x] = sh[255];
}

// two independent exclusive scans in one dispatch
__global__ __launch_bounds__(1024) void k_scan2x(const int* __restrict__ blk, int nb, int* __restrict__ blkoff,
                                                 const int* __restrict__ bcnt, int nb2, int* __restrict__ boff) {
    __shared__ int sh[1024];
    const int* in = blockIdx.x ? bcnt : blk;
    int n = blockIdx.x ? nb2 : nb;
    int* outp = blockIdx.x ? boff : blkoff;
    int tid = threadIdx.x;
    int v = (tid < n) ? in[tid] : 0;
    sh[tid] = v; __syncthreads();
    for (int off = 1; off < 1024; off <<= 1) {
        int t = (tid >= off) ? sh[tid - off] : 0;
        __syncthreads();
        sh[tid] += t;
        __syncthreads();
    }
    if (tid < n) outp[tid] = sh[tid] - v; // exclusive
}

// ---------------- bucketed edge scatter ----------------

__global__ __launch_bounds__(256) void k_bscatter(const int* __restrict__ src, const int* __restrict__ dst, int E,
                                                  const int* __restrict__ boff, int* __restrict__ gcur,
                                                  uint2* __restrict__ ebuf, int shift) {
    __shared__ int lh[512], lb[512];
    int tid = threadIdx.x;
    int base = blockIdx.x * 2048;
    for (int i = tid; i < 512; i += 256) lh[i] = 0;
    __syncthreads();
    int ms[8], md[8];
    #pragma unroll
    for (int j = 0; j < 8; ++j) {
        int idx = base + j * 256 + tid;
        if (idx < E) {
            ms[j] = src[idx]; md[j] = dst[idx];
            atomicAdd(&lh[md[j] >> shift], 1);
        } else md[j] = -1;
    }
    __syncthreads();
    for (int b = tid; b < 512; b += 256) {
        int c = lh[b];
        lb[b] = c ? atomicAdd(&gcur[b], c) : 0;
    }
    __syncthreads();
    for (int i = tid; i < 512; i += 256) lh[i] = 0;
    __syncthreads();
    #pragma unroll
    for (int j = 0; j < 8; ++j) {
        if (md[j] >= 0) {
            int b = md[j] >> shift;
            int r = atomicAdd(&lh[b], 1);
            ebuf[boff[b] + lb[b] + r] = make_uint2((unsigned)ms[j], (unsigned)md[j]);
        }
    }
}

// ---------------- CSR fill: colw[pos] = (src, dinv[src]); rs fold of blkoff ----------------

__global__ __launch_bounds__(256) void k_fill2(const uint2* __restrict__ ebuf, const int* __restrict__ bcnt,
                                               const int* __restrict__ boff, const int* __restrict__ rs,
                                               const int* __restrict__ blkoff, const float* __restrict__ dinv,
                                               uint2* __restrict__ colw, int shift) {
    __shared__ int lcur[256];
    int b = blockIdx.x;
    int n0 = b << shift;
    int cnt = bcnt[b], s = boff[b];
    int span = 1 << shift;
    for (int i = threadIdx.x; i < span; i += 256) lcur[i] = 0;
    __syncthreads();
    for (int i = threadIdx.x; i < cnt; i += 256) {
        uint2 e = ebuf[s + i];
        int d = (int)e.y;
        int sv = (int)e.x;
        int pos = rs[d] + blkoff[d >> 8] + atomicAdd(&lcur[d - n0], 1);
        colw[pos] = make_uint2((unsigned)sv, __builtin_bit_cast(unsigned, dinv[sv]));
    }
}

// ---------------- MFMA GEMM: 64-row tiles (782 blocks, 48KB LDS) — round-6 proven ----------------

__global__ __launch_bounds__(256) void k_gemm(const unsigned short* __restrict__ Abf,
                                              const float* __restrict__ Af,
                                              const unsigned short* __restrict__ Wimg,
                                              unsigned short* __restrict__ C, int N,
                                              const float* __restrict__ scale,
                                              const float* __restrict__ shift, int mode) {
    __shared__ unsigned short Asw[64 * 128];    // 16KB
    __shared__ unsigned short Wt[128 * 128];    // 32KB
    int tid = threadIdx.x;
    int r0 = blockIdx.x * 64;

    // ---- stage Wt: straight 32KB copy of the precomputed swizzled image ----
    {
        const uint4* wi = reinterpret_cast<const uint4*>(Wimg);
        uint4* wl = reinterpret_cast<uint4*>(Wt);
        #pragma unroll
        for (int j = 0; j < 8; ++j)
            wl[tid + j * 256] = wi[tid + j * 256];
    }
    // ---- stage A tile (64 rows x 128 cols, bf16, swizzled) ----
    if (mode == 0) {
        const float* ap = &Af[(size_t)r0 * 128];
        #pragma unroll
        for (int j = 0; j < 4; ++j) {
            int u = tid + j * 256;               // 16B units [0,1024)
            int row = u >> 4, cg = u & 15;       // cols cg*8..cg*8+7
            unsigned short t8[8] = {0,0,0,0,0,0,0,0};
            if (r0 + row < N) {
                float4 a0 = *reinterpret_cast<const float4*>(ap + row * 128 + cg * 8);
                float4 a1 = *reinterpret_cast<const float4*>(ap + row * 128 + cg * 8 + 4);
                t8[0]=f2bf(a0.x); t8[1]=f2bf(a0.y); t8[2]=f2bf(a0.z); t8[3]=f2bf(a0.w);
                t8[4]=f2bf(a1.x); t8[5]=f2bf(a1.y); t8[6]=f2bf(a1.z); t8[7]=f2bf(a1.w);
            }
            int byte = (row * 256 + cg * 16) ^ ((row & 7) << 4);
            *reinterpret_cast<uint4*>(reinterpret_cast<char*>(Asw) + byte) =
                *reinterpret_cast<const uint4*>(t8);
        }
    } else {
        const unsigned short* ap = &Abf[(size_t)r0 * 128];
        #pragma unroll
        for (int j = 0; j < 4; ++j) {
            int u = tid + j * 256;
            int row = u >> 4, cg = u & 15;
            unsigned short t8[8] = {0,0,0,0,0,0,0,0};
            if (r0 + row < N) {
                ushort4 v0 = *reinterpret_cast<const ushort4*>(ap + (size_t)row * 128 + cg * 8);
                ushort4 v1 = *reinterpret_cast<const ushort4*>(ap + (size_t)row * 128 + cg * 8 + 4);
                float4 sc0 = *reinterpret_cast<const float4*>(&scale[cg * 8]);
                float4 sc1 = *reinterpret_cast<const float4*>(&scale[cg * 8 + 4]);
                float4 sf0 = *reinterpret_cast<const float4*>(&shift[cg * 8]);
                float4 sf1 = *reinterpret_cast<const float4*>(&shift[cg * 8 + 4]);
                t8[0] = f2bf(fmaxf(bf2f(v0.x) * sc0.x + sf0.x, 0.f));
                t8[1] = f2bf(fmaxf(bf2f(v0.y) * sc0.y + sf0.y, 0.f));
                t8[2] = f2bf(fmaxf(bf2f(v0.z) * sc0.z + sf0.z, 0.f));
                t8[3] = f2bf(fmaxf(bf2f(v0.w) * sc0.w + sf0.w, 0.f));
                t8[4] = f2bf(fmaxf(bf2f(v1.x) * sc1.x + sf1.x, 0.f));
                t8[5] = f2bf(fmaxf(bf2f(v1.y) * sc1.y + sf1.y, 0.f));
                t8[6] = f2bf(fmaxf(bf2f(v1.z) * sc1.z + sf1.z, 0.f));
                t8[7] = f2bf(fmaxf(bf2f(v1.w) * sc1.w + sf1.w, 0.f));
            }
            int byte = (row * 256 + cg * 16) ^ ((row & 7) << 4);
            *reinterpret_cast<uint4*>(reinterpret_cast<char*>(Asw) + byte) =
                *reinterpret_cast<const uint4*>(t8);
        }
    }
    __syncthreads();

    // ---- MFMA: wave wv -> rows wv*16..+15; frags: 1 (M) x 8 (N), K-loop 4x32 ----
    int wv = tid >> 6, lane = tid & 63;
    int lr = lane & 15, lk = lane >> 4;
    f32x4 acc[8] = {};
    #pragma unroll
    for (int kk = 0; kk < 4; ++kk) {
        int ar = wv * 16 + lr;
        int abyte = (ar * 256 + kk * 64 + lk * 16) ^ ((ar & 7) << 4);
        bf16x8 af = *reinterpret_cast<const bf16x8*>(reinterpret_cast<const char*>(Asw) + abyte);
        bf16x8 bf[8];
        #pragma unroll
        for (int nf = 0; nf < 8; ++nf) {
            int bn = nf * 16 + lr;
            int byte = (bn * 256 + kk * 64 + lk * 16) ^ ((bn & 7) << 4);
            bf[nf] = *reinterpret_cast<const bf16x8*>(reinterpret_cast<const char*>(Wt) + byte);
        }
        #pragma unroll
        for (int nf = 0; nf < 8; ++nf)
            acc[nf] = __builtin_amdgcn_mfma_f32_16x16x32_bf16(af, bf[nf], acc[nf], 0, 0, 0);
    }
    __syncthreads();     // all reads of Asw/Wt done -> reuse Asw as C bounce
    #pragma unroll
    for (int nf = 0; nf < 8; ++nf)
        #pragma unroll
        for (int r = 0; r < 4; ++r) {
            int row = wv * 16 + lk * 4 + r;
            int colc = nf * 16 + lr;
            Asw[row * 128 + colc] = f2bf(acc[nf][r]);
        }
    __syncthreads();
    #pragma unroll
    for (int j = 0; j < 4; ++j) {
        int u = tid + j * 256;
        int row = u >> 4, cg = u & 15;
        if (r0 + row < N)
            *reinterpret_cast<uint4*>(&C[((size_t)(r0 + row)) * 128 + cg * 8]) =
                *reinterpret_cast<const uint4*>(&Asw[row * 128 + cg * 8]);
    }
}

// ---------------- aggregation + fused BN-stats partials (round-6 proven; rs fold) ----------------

__global__ __launch_bounds__(256) void k_agg(const unsigned short* __restrict__ t, const uint2* __restrict__ colw,
                                             const int* __restrict__ rs, const int* __restrict__ blkoff,
                                             const int* __restrict__ deg,
                                             const float* __restrict__ dinv, const float* __restrict__ bias,
                                             unsigned short* __restrict__ out, int N,
                                             float* __restrict__ p1, float* __restrict__ p2) {
    __shared__ uint2 ec[4][64];
    __shared__ float sh[4][64][4];
    int wv = threadIdx.x >> 6, lane = threadIdx.x & 63;
    const ushort2* tp = reinterpret_cast<const ushort2*>(t);
    float b0 = bias[2 * lane], b1 = bias[2 * lane + 1];
    float s1x = 0.f, s1y = 0.f, s2x = 0.f, s2y = 0.f;
    for (int w = blockIdx.x * 4 + wv; w < N; w += gridDim.x * 4) {
        int start = rs[w] + blkoff[w >> 8];
        int cnt = deg[w];
        float di = dinv[w];
        float ax = 0.f, ay = 0.f;
        for (int base = 0; base < cnt; base += 64) {
            int m = min(cnt - base, 64);
            if (lane < m) ec[wv][lane] = colw[start + base + lane];
            asm volatile("s_waitcnt lgkmcnt(0)" ::: "memory");   // wave-private LDS visibility
            int e = 0;
            for (; e + 4 <= m; e += 4) {
                uint2 e0 = ec[wv][e], e1 = ec[wv][e + 1], e2 = ec[wv][e + 2], e3 = ec[wv][e + 3];
                ushort2 v0 = tp[(size_t)e0.x * 64 + lane];
                ushort2 v1 = tp[(size_t)e1.x * 64 + lane];
                ushort2 v2 = tp[(size_t)e2.x * 64 + lane];
                ushort2 v3 = tp[(size_t)e3.x * 64 + lane];
                float w0 = __builtin_bit_cast(float, e0.y), w1 = __builtin_bit_cast(float, e1.y);
                float w2 = __builtin_bit_cast(float, e2.y), w3 = __builtin_bit_cast(float, e3.y);
                ax += w0 * bf2f(v0.x) + w1 * bf2f(v1.x) + w2 * bf2f(v2.x) + w3 * bf2f(v3.x);
                ay += w0 * bf2f(v0.y) + w1 * bf2f(v1.y) + w2 * bf2f(v2.y) + w3 * bf2f(v3.y);
            }
            for (; e < m; ++e) {
                uint2 ee = ec[wv][e];
                ushort2 v = tp[(size_t)ee.x * 64 + lane];
                float ww = __builtin_bit_cast(float, ee.y);
                ax += ww * bf2f(v.x);
                ay += ww * bf2f(v.y);
            }
        }
        ushort2 self = tp[(size_t)w * 64 + lane];
        ushort2 o;
        o.x = f2bf(di * ax + di * di * bf2f(self.x) + b0);
        o.y = f2bf(di * ay + di * di * bf2f(self.y) + b1);
        reinterpret_cast<ushort2*>(out)[(size_t)w * 64 + lane] = o;
        float rx = bf2f(o.x), ry = bf2f(o.y);   // stats on STORED values (self-consistent BN)
        s1x += rx; s1y += ry; s2x += rx * rx; s2y += ry * ry;
    }
    sh[wv][lane][0] = s1x; sh[wv][lane][1] = s1y; sh[wv][lane][2] = s2x; sh[wv][lane][3] = s2y;
    __syncthreads();
    int tid = threadIdx.x;
    if (tid < 64) {
        float a0 = 0.f, a1 = 0.f, a2 = 0.f, a3 = 0.f;
        #pragma unroll
        for (int r = 0; r < 4; ++r) {
            a0 += sh[r][tid][0]; a1 += sh[r][tid][1];
            a2 += sh[r][tid][2]; a3 += sh[r][tid][3];
        }
        p1[(size_t)blockIdx.x * 128 + 2 * tid]     = a0;
        p1[(size_t)blockIdx.x * 128 + 2 * tid + 1] = a1;
        p2[(size_t)blockIdx.x * 128 + 2 * tid]     = a2;
        p2[(size_t)blockIdx.x * 128 + 2 * tid + 1] = a3;
    }
}

// ---------------- BN stats partial reductions (two-stage, proven) ----------------

__global__ __launch_bounds__(128) void k_statsmid(const float* __restrict__ p1, const float* __restrict__ p2,
                                                  int rows, float* __restrict__ pm1, float* __restrict__ pm2) {
    int c = threadIdx.x, b = blockIdx.x;
    int r0 = b * rows;
    float s1 = 0.f, s2 = 0.f;
    #pragma unroll 4
    for (int r = 0; r < rows; ++r) {
        s1 += p1[(size_t)(r0 + r) * 128 + c];
        s2 += p2[(size_t)(r0 + r) * 128 + c];
    }
    pm1[b * 128 + c] = s1;
    pm2[b * 128 + c] = s2;
}

__global__ __launch_bounds__(1024) void k_stats2(const float* __restrict__ p1, const float* __restrict__ p2,
                                                 int nb, int N,
                                                 const float* __restrict__ g, const float* __restrict__ be,
                                                 float* __restrict__ scale, float* __restrict__ shift) {
    __shared__ double sh1[1024], sh2[1024];
    int tid = threadIdx.x;
    int c = tid & 127, seg = tid >> 7;       // 8 segments
    double s1 = 0.0, s2 = 0.0;
    int b = seg;
    for (; b + 32 <= nb; b += 32) {
        double a0 = p1[(b      ) * 128 + c], q0 = p2[(b      ) * 128 + c];
        double a1 = p1[(b +  8) * 128 + c], q1 = p2[(b +  8) * 128 + c];
        double a2 = p1[(b + 16) * 128 + c], q2 = p2[(b + 16) * 128 + c];
        double a3 = p1[(b + 24) * 128 + c], q3 = p2[(b + 24) * 128 + c];
        s1 += (a0 + a1) + (a2 + a3);
        s2 += (q0 + q1) + (q2 + q3);
    }
    for (; b < nb; b += 8) { s1 += p1[b * 128 + c]; s2 += p2[b * 128 + c]; }
    sh1[tid] = s1; sh2[tid] = s2;
    __syncthreads();
    #pragma unroll
    for (int s = 4; s >= 1; s >>= 1) {
        if (seg < s) {
            sh1[tid] += sh1[tid + s * 128];
            sh2[tid] += sh2[tid + s * 128];
        }
        __syncthreads();
    }
    if (tid < 128) {
        double mu = sh1[c] / N;
        double var = sh2[c] / N - mu * mu;
        double inv = 1.0 / sqrt(var + (double)EPSBN);
        scale[c] = (float)((double)g[c] * inv);
        shift[c] = (float)((double)be[c] - mu * (double)g[c] * inv);
    }
}

// ---------------- pooling + output head (split form — round-10 proven) ----------------

__global__ __launch_bounds__(256) void k_pool(const unsigned short* __restrict__ h, const int* __restrict__ batch,
                                              const float* __restrict__ scale, const float* __restrict__ shift,
                                              const float* __restrict__ Wout, int N, int G,
                                              float* __restrict__ pool, int* __restrict__ cnt) {
    __shared__ float pl[64];
    __shared__ int cl[64];
    int tid = threadIdx.x;
    if (tid < 64) { pl[tid] = 0.f; cl[tid] = 0; }
    __syncthreads();
    int wv = tid >> 6, lane = tid & 63;
    float sc0 = scale[2 * lane], sc1 = scale[2 * lane + 1];
    float sf0 = shift[2 * lane], sf1 = shift[2 * lane + 1];
    float w0 = Wout[2 * lane], w1 = Wout[2 * lane + 1];
    const ushort2* hp = reinterpret_cast<const ushort2*>(h);
    int wid = blockIdx.x * 4 + wv;
    int stride = gridDim.x * 4;
    for (int i = wid; i < N; i += stride * 4) {
        int i1 = i + stride, i2 = i + 2 * stride, i3 = i + 3 * stride;
        float s0 = 0.f, s1 = 0.f, s2 = 0.f, s3 = 0.f;
        {
            ushort2 v = hp[(size_t)i * 64 + lane];
            s0 = fmaxf(bf2f(v.x) * sc0 + sf0, 0.f) * w0 + fmaxf(bf2f(v.y) * sc1 + sf1, 0.f) * w1;
        }
        if (i1 < N) {
            ushort2 v = hp[(size_t)i1 * 64 + lane];
            s1 = fmaxf(bf2f(v.x) * sc0 + sf0, 0.f) * w0 + fmaxf(bf2f(v.y) * sc1 + sf1, 0.f) * w1;
        }
        if (i2 < N) {
            ushort2 v = hp[(size_t)i2 * 64 + lane];
            s2 = fmaxf(bf2f(v.x) * sc0 + sf0, 0.f) * w0 + fmaxf(bf2f(v.y) * sc1 + sf1, 0.f) * w1;
        }
        if (i3 < N) {
            ushort2 v = hp[(size_t)i3 * 64 + lane];
            s3 = fmaxf(bf2f(v.x) * sc0 + sf0, 0.f) * w0 + fmaxf(bf2f(v.y) * sc1 + sf1, 0.f) * w1;
        }
        #pragma unroll
        for (int o = 32; o > 0; o >>= 1) {
            s0 += __shfl_down(s0, o); s1 += __shfl_down(s1, o);
            s2 += __shfl_down(s2, o); s3 += __shfl_down(s3, o);
        }
        if (lane == 0) {
            atomicAdd(&pl[batch[i]], s0); atomicAdd(&cl[batch[i]], 1);
            if (i1 < N) { atomicAdd(&pl[batch[i1]], s1); atomicAdd(&cl[batch[i1]], 1); }
            if (i2 < N) { atomicAdd(&pl[batch[i2]], s2); atomicAdd(&cl[batch[i2]], 1); }
            if (i3 < N) { atomicAdd(&pl[batch[i3]], s3); atomicAdd(&cl[batch[i3]], 1); }
        }
    }
    __syncthreads();
    if (tid < 64) {
        atomicAdd(&pool[tid], pl[tid]);
        atomicAdd(&cnt[tid], cl[tid]);
    }
}

__global__ void k_final(const float* __restrict__ pool, const int* __restrict__ cnt,
                        const float* __restrict__ bout, int G, float* __restrict__ out) {
    int g = blockIdx.x * blockDim.x + threadIdx.x;
    if (g < G) {
        float c = fmaxf((float)cnt[g], 1.f);
        float p = pool[g] / c + bout[0];
        out[g] = 1.f / (1.f + expf(-p));
    }
}

// ---------------- launch ----------------

extern "C" void kernel_launch(void* const* d_in, const int* in_sizes, int n_in,
                              void* d_out, int out_size, void* d_ws, size_t ws_size,
                              hipStream_t stream) {
    const float* x    = (const float*)d_in[0];
    const int*   ei   = (const int*)d_in[1];
    const int*   batch= (const int*)d_in[2];
    const float* W0p  = (const float*)d_in[3];
    const float* b0p  = (const float*)d_in[4];
    const float* g0p  = (const float*)d_in[5];
    const float* be0p = (const float*)d_in[6];
    const float* W1p  = (const float*)d_in[7];
    const float* b1p  = (const float*)d_in[8];
    const float* g1p  = (const float*)d_in[9];
    const float* be1p = (const float*)d_in[10];
    const float* W2p  = (const float*)d_in[11];
    const float* b2p  = (const float*)d_in[12];
    const float* g2p  = (const float*)d_in[13];
    const float* be2p = (const float*)d_in[14];
    const float* Woutp= (const float*)d_in[15];
    const float* boutp= (const float*)d_in[16];

    int N = in_sizes[0] / 128;
    int E = in_sizes[1] / 2;
    int G = out_size;
    const int* src = ei;
    const int* dst = ei + E;

    // bucket geometry: <=512 buckets, <=256 nodes each
    int shiftB = 7;
    while ((((N + (1 << shiftB) - 1) >> shiftB) > 512) && shiftB < 8) ++shiftB;
    int nbuck = (N + (1 << shiftB) - 1) >> shiftB;

    char* p = (char*)d_ws;
    auto alloc = [&](size_t bytes) {
        void* q = (void*)p;
        p += (bytes + 255) & ~(size_t)255;
        return q;
    };
    unsigned short* Bt  = (unsigned short*)alloc((size_t)N * 128 * 2);  // bf16 t (gemm out)
    unsigned short* Bh  = (unsigned short*)alloc((size_t)N * 128 * 2);  // bf16 h (agg out)
    uint2*  colw   = (uint2*) alloc((size_t)E * 8);
    uint2*  ebuf   = (uint2*) alloc((size_t)E * 8);
    int*    rsA    = (int*)   alloc((size_t)N * 4);
    float*  dinv   = (float*) alloc((size_t)N * 4);
    int*    blk    = (int*)   alloc(1024 * 4);
    int*    blkoff = (int*)   alloc(1024 * 4);
    int*    boff   = (int*)   alloc(512 * 4);
    unsigned short* Wimg = (unsigned short*)alloc(3 * 16384 * 2);
    float*  p1     = (float*) alloc((size_t)AGG_BLOCKS * 128 * 4);
    float*  p2     = (float*) alloc((size_t)AGG_BLOCKS * 128 * 4);
    float*  pm1    = (float*) alloc(128 * 128 * 4);
    float*  pm2    = (float*) alloc(128 * 128 * 4);
    float*  scale  = (float*) alloc(128 * 4);
    float*  shift  = (float*) alloc(128 * 4);
    // zero-init group: contiguous -> single memset
    char*   z0     = p;
    int*    deg    = (int*)   alloc((size_t)N * 4);
    int*    bcnt   = (int*)   alloc(512 * 4);
    int*    gcur   = (int*)   alloc(512 * 4);
    float*  pool   = (float*) alloc(64 * 4);
    int*    cnt    = (int*)   alloc(64 * 4);
    size_t  zbytes = (size_t)(p - z0);

    hipMemsetAsync(z0, 0, zbytes, stream);

    int nb = (N + 255) / 256;
    k_prep    <<<259, 256, 0, stream>>>(W0p, W1p, W2p, Wimg, dst, E, deg, bcnt, shiftB);
    k_scan1   <<<nb, 256, 0, stream>>>(deg, N, rsA, blk, dinv);
    k_scan2x  <<<2, 1024, 0, stream>>>(blk, nb, blkoff, bcnt, 512, boff);
    k_bscatter<<<(E + 2047) / 2048, 256, 0, stream>>>(src, dst, E, boff, gcur, ebuf, shiftB);
    k_fill2   <<<nbuck, 256, 0, stream>>>(ebuf, bcnt, boff, rsA, blkoff, dinv, colw, shiftB);

    int gemmBlocks = (N + 63) / 64;
    int midRows = AGG_BLOCKS / 128;

    // layer 0
    k_gemm    <<<gemmBlocks, 256, 0, stream>>>(nullptr, x, Wimg, Bt, N, scale, shift, 0);
    k_agg     <<<AGG_BLOCKS, 256, 0, stream>>>(Bt, colw, rsA, blkoff, deg, dinv, b0p, Bh, N, p1, p2);
    k_statsmid<<<128, 128, 0, stream>>>(p1, p2, midRows, pm1, pm2);
    k_stats2  <<<1, 1024, 0, stream>>>(pm1, pm2, 128, N, g0p, be0p, scale, shift);
    // layer 1
    k_gemm    <<<gemmBlocks, 256, 0, stream>>>(Bh, nullptr, Wimg + 16384, Bt, N, scale, shift, 1);
    k_agg     <<<AGG_BLOCKS, 256, 0, stream>>>(Bt, colw, rsA, blkoff, deg, dinv, b1p, Bh, N, p1, p2);
    k_statsmid<<<128, 128, 0, stream>>>(p1, p2, midRows, pm1, pm2);
    k_stats2  <<<1, 1024, 0, stream>>>(pm1, pm2, 128, N, g1p, be1p, scale, shift);
    // layer 2
    k_gemm    <<<gemmBlocks, 256, 0, stream>>>(Bh, nullptr, Wimg + 32768, Bt, N, scale, shift, 1);
    k_agg     <<<AGG_BLOCKS, 256, 0, stream>>>(Bt, colw, rsA, blkoff, deg, dinv, b2p, Bh, N, p1, p2);
    k_statsmid<<<128, 128, 0, stream>>>(p1, p2, midRows, pm1, pm2);
    k_stats2  <<<1, 1024, 0, stream>>>(pm1, pm2, 128, N, g2p, be2p, scale, shift);
    // head
    k_pool <<<1024, 256, 0, stream>>>(Bh, batch, scale, shift, Woutp, N, G, pool, cnt);
    k_final<<<1, 64, 0, stream>>>(pool, cnt, boutp, G, (float*)d_out);
}